// Round 16
// baseline (194.721 us; speedup 1.0000x reference)
//
#include <hip/hip_runtime.h>
#include <math.h>

#define BGRAPH 128
#define ETOT   (128*4096)   // 524288
#define EPG    4096
#define K1 256
#define K2 128
#define K3 64

// ---------------- double-buffered GEMM, BM=64 (for L2/L3) ----------------
__global__ __launch_bounds__(256) void gemm_db64(const float* __restrict__ X,
                                                 const float* __restrict__ W,
                                                 float* __restrict__ Y){
  __shared__ float sA[2][64*17];
  __shared__ float sB[2][16*192];
  int t = threadIdx.x;
  int row0 = blockIdx.x * 64;
  int tx = t & 15;
  int ty = t >> 4;
  float acc[4][8];
  #pragma unroll
  for (int i = 0; i < 4; ++i)
    #pragma unroll
    for (int j = 0; j < 8; ++j) acc[i][j] = 0.f;

  float4 xv0, wv0, wv1;
  int xrow = t >> 2, xc4 = t & 3;
  int w0kr = t >> 5, w0c4 = t & 31;
  int f1 = t + 256;
  int w1kr = f1 >> 5, w1c4 = f1 & 31;

  // prologue: tile 0
  xv0 = *(const float4*)(X + (size_t)(row0 + xrow)*128 + xc4*4);
  wv0 = *(const float4*)(W + (size_t)w0kr*128 + w0c4*4);
  wv1 = *(const float4*)(W + (size_t)w1kr*128 + w1c4*4);
  {
    float* a = sA[0]; float* b = sB[0];
    a[xrow*17 + xc4*4+0] = xv0.x; a[xrow*17 + xc4*4+1] = xv0.y;
    a[xrow*17 + xc4*4+2] = xv0.z; a[xrow*17 + xc4*4+3] = xv0.w;
    *(float4*)&b[w0kr*192 + (w0c4>>1)*12 + (w0c4&1)*4] = wv0;
    *(float4*)&b[w1kr*192 + (w1c4>>1)*12 + (w1c4&1)*4] = wv1;
  }
  __syncthreads();

  for (int s = 0; s < 8; ++s){
    if (s < 7){
      int k0 = (s+1)*16;
      xv0 = *(const float4*)(X + (size_t)(row0 + xrow)*128 + k0 + xc4*4);
      wv0 = *(const float4*)(W + (size_t)(k0 + w0kr)*128 + w0c4*4);
      wv1 = *(const float4*)(W + (size_t)(k0 + w1kr)*128 + w1c4*4);
    }
    const float* a = sA[s&1];
    const float* b = sB[s&1];
    #pragma unroll
    for (int kk = 0; kk < 16; ++kk){
      float4 b0 = *(const float4*)&b[kk*192 + tx*12];
      float4 b1 = *(const float4*)&b[kk*192 + tx*12 + 4];
      float aa[4];
      #pragma unroll
      for (int i = 0; i < 4; ++i) aa[i] = a[(ty*4 + i)*17 + kk];
      float bb[8] = {b0.x,b0.y,b0.z,b0.w,b1.x,b1.y,b1.z,b1.w};
      #pragma unroll
      for (int i = 0; i < 4; ++i)
        #pragma unroll
        for (int j = 0; j < 8; ++j)
          acc[i][j] = fmaf(aa[i], bb[j], acc[i][j]);
    }
    if (s < 7){
      float* an = sA[(s+1)&1]; float* bn = sB[(s+1)&1];
      an[xrow*17 + xc4*4+0] = xv0.x; an[xrow*17 + xc4*4+1] = xv0.y;
      an[xrow*17 + xc4*4+2] = xv0.z; an[xrow*17 + xc4*4+3] = xv0.w;
      *(float4*)&bn[w0kr*192 + (w0c4>>1)*12 + (w0c4&1)*4] = wv0;
      *(float4*)&bn[w1kr*192 + (w1c4>>1)*12 + (w1c4&1)*4] = wv1;
      __syncthreads();
    }
  }
  #pragma unroll
  for (int i = 0; i < 4; ++i){
    float* yr = Y + (size_t)(row0 + ty*4 + i)*128 + tx*8;
    *(float4*)yr       = *(float4*)&acc[i][0];
    *(float4*)(yr + 4) = *(float4*)&acc[i][4];
  }
}

// ---------------- fused L1: blocks 0..511 GEMM (BM=128, dbuf), 512..639 scanfill ----------------
__global__ __launch_bounds__(256) void fused_l1(const float* __restrict__ X,
    const float* __restrict__ W, float* __restrict__ Y,
    const int* __restrict__ src, const int* __restrict__ dst,
    int* __restrict__ off, int* __restrict__ cnt, float* __restrict__ dinv,
    int* __restrict__ csr, float* __restrict__ coef, int* __restrict__ ecnt){
  extern __shared__ float smem[];
  int t = threadIdx.x;
  if (blockIdx.x < 512){
    float* sA0 = smem;                 // 128*17 = 2176
    float* sA1 = smem + 2176;
    float* sB0 = smem + 4352;          // 16*192 = 3072
    float* sB1 = smem + 4352 + 3072;
    int row0 = blockIdx.x * 128;
    int tx = t & 15;
    int ty = t >> 4;
    float acc[8][8];
    #pragma unroll
    for (int i = 0; i < 8; ++i)
      #pragma unroll
      for (int j = 0; j < 8; ++j) acc[i][j] = 0.f;

    int f1 = t + 256;
    int x0r = t >> 2,  x0c = t & 3;
    int x1r = f1 >> 2, x1c = f1 & 3;
    int w0k = t >> 5,  w0c = t & 31;
    int w1k = f1 >> 5, w1c = f1 & 31;
    float4 xv0, xv1, wv0, wv1;

    xv0 = *(const float4*)(X + (size_t)(row0 + x0r)*128 + x0c*4);
    xv1 = *(const float4*)(X + (size_t)(row0 + x1r)*128 + x1c*4);
    wv0 = *(const float4*)(W + (size_t)w0k*128 + w0c*4);
    wv1 = *(const float4*)(W + (size_t)w1k*128 + w1c*4);
    {
      sA0[x0r*17 + x0c*4+0] = xv0.x; sA0[x0r*17 + x0c*4+1] = xv0.y;
      sA0[x0r*17 + x0c*4+2] = xv0.z; sA0[x0r*17 + x0c*4+3] = xv0.w;
      sA0[x1r*17 + x1c*4+0] = xv1.x; sA0[x1r*17 + x1c*4+1] = xv1.y;
      sA0[x1r*17 + x1c*4+2] = xv1.z; sA0[x1r*17 + x1c*4+3] = xv1.w;
      *(float4*)&sB0[w0k*192 + (w0c>>1)*12 + (w0c&1)*4] = wv0;
      *(float4*)&sB0[w1k*192 + (w1c>>1)*12 + (w1c&1)*4] = wv1;
    }
    __syncthreads();

    for (int s = 0; s < 8; ++s){
      if (s < 7){
        int k0 = (s+1)*16;
        xv0 = *(const float4*)(X + (size_t)(row0 + x0r)*128 + k0 + x0c*4);
        xv1 = *(const float4*)(X + (size_t)(row0 + x1r)*128 + k0 + x1c*4);
        wv0 = *(const float4*)(W + (size_t)(k0 + w0k)*128 + w0c*4);
        wv1 = *(const float4*)(W + (size_t)(k0 + w1k)*128 + w1c*4);
      }
      const float* a = (s&1) ? sA1 : sA0;
      const float* b = (s&1) ? sB1 : sB0;
      #pragma unroll
      for (int kk = 0; kk < 16; ++kk){
        float4 b0 = *(const float4*)&b[kk*192 + tx*12];
        float4 b1 = *(const float4*)&b[kk*192 + tx*12 + 4];
        float aa[8];
        #pragma unroll
        for (int i = 0; i < 8; ++i) aa[i] = a[(ty*8 + i)*17 + kk];
        float bb[8] = {b0.x,b0.y,b0.z,b0.w,b1.x,b1.y,b1.z,b1.w};
        #pragma unroll
        for (int i = 0; i < 8; ++i)
          #pragma unroll
          for (int j = 0; j < 8; ++j)
            acc[i][j] = fmaf(aa[i], bb[j], acc[i][j]);
      }
      if (s < 7){
        float* an = (s&1) ? sA0 : sA1;
        float* bn = (s&1) ? sB0 : sB1;
        an[x0r*17 + x0c*4+0] = xv0.x; an[x0r*17 + x0c*4+1] = xv0.y;
        an[x0r*17 + x0c*4+2] = xv0.z; an[x0r*17 + x0c*4+3] = xv0.w;
        an[x1r*17 + x1c*4+0] = xv1.x; an[x1r*17 + x1c*4+1] = xv1.y;
        an[x1r*17 + x1c*4+2] = xv1.z; an[x1r*17 + x1c*4+3] = xv1.w;
        *(float4*)&bn[w0k*192 + (w0c>>1)*12 + (w0c&1)*4] = wv0;
        *(float4*)&bn[w1k*192 + (w1c>>1)*12 + (w1c&1)*4] = wv1;
        __syncthreads();
      }
    }
    #pragma unroll
    for (int i = 0; i < 8; ++i){
      float* yr = Y + (size_t)(row0 + ty*8 + i)*128 + tx*8;
      *(float4*)yr       = *(float4*)&acc[i][0];
      *(float4*)(yr + 4) = *(float4*)&acc[i][4];
    }
  } else {
    // scanfill: count -> scan -> fill
    int g = blockIdx.x - 512;
    int*   sc  = (int*)smem;            // 512
    int*   sp  = sc + 512;              // 256
    int*   cur = sp + 256;              // 512
    float* sdv = (float*)(cur + 512);   // 512
    sc[t] = 0; sc[t + 256] = 0;
    __syncthreads();
    const int* sg = src + g*EPG;
    const int* dg = dst + g*EPG;
    for (int e = t; e < EPG; e += 256)
      atomicAdd(&sc[dg[e] & 511], 1);
    __syncthreads();
    int a = sc[2*t], b = sc[2*t+1];
    int pair = a + b;
    sp[t] = pair;
    __syncthreads();
    for (int d = 1; d < 256; d <<= 1){
      int u = (t >= d) ? sp[t-d] : 0;
      __syncthreads();
      sp[t] += u;
      __syncthreads();
    }
    int pre0 = sp[t] - pair;
    int pre1 = pre0 + a;
    float dv0 = rsqrtf((float)a + 1.f);
    float dv1 = rsqrtf((float)b + 1.f);
    sdv[2*t]   = dv0;  sdv[2*t+1] = dv1;
    dinv[g*512 + 2*t]   = dv0;  dinv[g*512 + 2*t+1] = dv1;
    cnt[g*512 + 2*t]    = a;    cnt[g*512 + 2*t+1]  = b;
    off[g*512 + 2*t]    = g*EPG + pre0;
    off[g*512 + 2*t+1]  = g*EPG + pre1;
    sc[2*t] = pre0; sc[2*t+1] = pre1;
    cur[2*t] = 0;   cur[2*t+1] = 0;
    if (t == 0) ecnt[g] = EPG;
    __syncthreads();
    int* cg = csr + g*EPG;
    float* cf = coef + g*EPG;
    for (int e = t; e < EPG; e += 256){
      int s = sg[e], dl = dg[e] & 511;
      int slot = sc[dl] + atomicAdd(&cur[dl], 1);
      cg[slot]  = s;
      cf[slot]  = sdv[s & 511] * sdv[dl];
    }
  }
}

// ---------------- fused aggregation + score GEMV, graph->XCD pinned, unroll x8 ----------------
__global__ void gather_agg(const float* __restrict__ hx, const int* __restrict__ csr,
                           const float* __restrict__ coef,
                           const int* __restrict__ off, const int* __restrict__ cnt,
                           const float* __restrict__ dinv, const float* __restrict__ bias,
                           const float* __restrict__ Ws, float* __restrict__ out,
                           float* __restrict__ hs, int npg, int n){
  int bpg = npg >> 3;
  int x = blockIdx.x >> 3, r = blockIdx.x & 7;
  int pos = x % bpg, grp = x / bpg;
  int g = grp*8 + r;
  int t = threadIdx.x;
  int node = g*npg + pos*8 + (t >> 5);
  int fl = t & 31;
  float dd = dinv[node];
  int o = off[node], deg = cnt[node];
  const float4* rows = (const float4*)hx;
  float4 a0 = {0,0,0,0}, a1 = {0,0,0,0}, a2 = {0,0,0,0}, a3 = {0,0,0,0};
  int e = o, end = o + deg;
  for (; e + 7 < end; e += 8){
    int sx[8]; float cx[8]; float4 vv[8];
    #pragma unroll
    for (int q = 0; q < 8; ++q){ sx[q] = csr[e+q]; cx[q] = coef[e+q]; }
    #pragma unroll
    for (int q = 0; q < 8; ++q) vv[q] = rows[(size_t)sx[q]*32 + fl];
    #pragma unroll
    for (int q = 0; q < 8; ++q){
      float4& aq = (q&3)==0 ? a0 : ((q&3)==1 ? a1 : ((q&3)==2 ? a2 : a3));
      aq.x = fmaf(cx[q], vv[q].x, aq.x);
      aq.y = fmaf(cx[q], vv[q].y, aq.y);
      aq.z = fmaf(cx[q], vv[q].z, aq.z);
      aq.w = fmaf(cx[q], vv[q].w, aq.w);
    }
  }
  for (; e + 3 < end; e += 4){
    int sx[4]; float cx[4]; float4 vv[4];
    #pragma unroll
    for (int q = 0; q < 4; ++q){ sx[q] = csr[e+q]; cx[q] = coef[e+q]; }
    #pragma unroll
    for (int q = 0; q < 4; ++q) vv[q] = rows[(size_t)sx[q]*32 + fl];
    #pragma unroll
    for (int q = 0; q < 4; ++q){
      float4& aq = (q==0) ? a0 : ((q==1) ? a1 : ((q==2) ? a2 : a3));
      aq.x = fmaf(cx[q], vv[q].x, aq.x);
      aq.y = fmaf(cx[q], vv[q].y, aq.y);
      aq.z = fmaf(cx[q], vv[q].z, aq.z);
      aq.w = fmaf(cx[q], vv[q].w, aq.w);
    }
  }
  for (; e < end; ++e){
    int s0 = csr[e];
    float c0 = coef[e];
    float4 v0 = rows[(size_t)s0*32 + fl];
    a0.x=fmaf(c0,v0.x,a0.x); a0.y=fmaf(c0,v0.y,a0.y); a0.z=fmaf(c0,v0.z,a0.z); a0.w=fmaf(c0,v0.w,a0.w);
  }
  float4 own = rows[(size_t)node*32 + fl];
  float4 bv  = ((const float4*)bias)[fl];
  float d2 = dd*dd;
  float4 rr;
  rr.x = fmaxf(fmaf(d2, own.x, (a0.x+a1.x)+(a2.x+a3.x) + bv.x), 0.f);
  rr.y = fmaxf(fmaf(d2, own.y, (a0.y+a1.y)+(a2.y+a3.y) + bv.y), 0.f);
  rr.z = fmaxf(fmaf(d2, own.z, (a0.z+a1.z)+(a2.z+a3.z) + bv.z), 0.f);
  rr.w = fmaxf(fmaf(d2, own.w, (a0.w+a1.w)+(a2.w+a3.w) + bv.w), 0.f);
  ((float4*)(out + (size_t)node*128))[fl] = rr;
  float4 w = ((const float4*)Ws)[fl];
  float p = rr.x*w.x + rr.y*w.y + rr.z*w.z + rr.w*w.w;
  p += __shfl_xor(p, 16);
  p += __shfl_xor(p, 8);
  p += __shfl_xor(p, 4);
  p += __shfl_xor(p, 2);
  p += __shfl_xor(p, 1);
  if (fl == 0) hs[node] = p;
}

// ---------------- per-graph mega (1024 thr) ----------------
template<int NP, int K, int HASNEXT, int FIRST, int RAW>
__global__ __launch_bounds__(1024) void mega(
    const float* __restrict__ hs, const int* __restrict__ csr_in,
    const float* __restrict__ coef_in, const int* __restrict__ off_in,
    const int* __restrict__ cnt_in, const float* __restrict__ dinv_in,
    const float* __restrict__ bs, const float* __restrict__ Hm,
    float* __restrict__ xnew, float* __restrict__ out,
    const int* __restrict__ pes, const int* __restrict__ ped,
    const int* __restrict__ ecnt_in,
    int* __restrict__ off_o, int* __restrict__ cnt_o, float* __restrict__ dinv_o,
    int* __restrict__ csr_o, int* __restrict__ dst_o, float* __restrict__ coef_o,
    int* __restrict__ ecnt_o)
{
  constexpr int R   = 1024 / NP;
  constexpr int LNP = (NP == 512) ? 9 : ((NP == 256) ? 8 : 7);
  __shared__ int   ss[EPG];
  __shared__ int   sd[EPG];
  __shared__ float scf[RAW ? 1 : EPG];
  __shared__ float shs[NP];
  __shared__ float spart[1024];
  __shared__ float sv[NP];
  __shared__ int   si[NP];
  __shared__ int   lnew[NP];
  __shared__ int   lperm[K];
  __shared__ float ltanh[K];
  __shared__ float smx[1024], ssm[1024];
  __shared__ int   sc[K], sp2[K], cur[K];
  __shared__ float sdvn[K];
  int g = blockIdx.x, t = threadIdx.x;
  int E_in = ecnt_in[g];

  if (t < NP){ shs[t] = hs[g*NP + t]; lnew[t] = -1; }
  for (int e = t; e < E_in; e += 1024){
    ss[e] = pes[g*EPG + e];
    sd[e] = ped[g*EPG + e];
    if (!RAW) scf[e] = coef_in[g*EPG + e];
  }
  __syncthreads();

  int n = t & (NP-1);
  int p = t >> LNP;
  {
    float a = 0.f;
    if (RAW){
      int lo = off_in[g*NP + n], deg = cnt_in[g*NP + n];
      for (int e = lo + p; e < lo + deg; e += R)
        a = fmaf(coef_in[e], shs[csr_in[e] & (NP-1)], a);
    } else {
      int lo = off_in[g*NP + n] - g*EPG, deg = cnt_in[g*NP + n];
      for (int e = lo + p; e < lo + deg; e += R)
        a = fmaf(scf[e], shs[ss[e] & (NP-1)], a);
    }
    spart[t] = a;
  }
  __syncthreads();
  float v = -INFINITY; int idx = n;
  if (p == 0){
    float a = spart[n];
    #pragma unroll
    for (int q = 1; q < R; ++q) a += spart[n + q*NP];
    float dd = dinv_in[g*NP + n];
    v = a + fmaf(dd*dd, shs[n], bs[0]);
  }
  #pragma unroll
  for (int ksz = 2; ksz <= NP; ksz <<= 1){
    #pragma unroll
    for (int j = ksz >> 1; j > 0; j >>= 1){
      float v2 = 0.f; int i2 = 0;
      if (j >= 64){
        __syncthreads();
        if (t < NP){ sv[t] = v; si[t] = idx; }
        __syncthreads();
        if (t < NP){ v2 = sv[t^j]; i2 = si[t^j]; }
      } else if (t < NP){
        v2 = __shfl_xor(v, j);
        i2 = __shfl_xor(idx, j);
      }
      if (t < NP){
        bool dir = ((t & ksz) == 0);
        bool pf = (v2 > v) || (v2 == v && i2 < idx);
        bool lower = (t & j) == 0;
        if (pf == (lower ? dir : !dir)){ v = v2; idx = i2; }
      }
    }
  }
  if (t < K){
    lperm[t] = idx;
    lnew[idx] = t;
    ltanh[t] = tanhf(v);
  }
  __syncthreads();

  {
    int f = t & 127, q = t >> 7;
    float mx = -INFINITY, sm = 0.f;
    for (int j = q; j < K; j += 8){
      float val = Hm[(size_t)(g*NP + lperm[j])*128 + f] * ltanh[j];
      xnew[(size_t)(g*K + j)*128 + f] = val;
      mx = fmaxf(mx, val); sm += val;
    }
    smx[t] = mx; ssm[t] = sm;
  }
  __syncthreads();
  if (t < 128){
    float mx = smx[t], sm = ssm[t];
    #pragma unroll
    for (int q = 1; q < 8; ++q){ mx = fmaxf(mx, smx[q*128+t]); sm += ssm[q*128+t]; }
    if (FIRST){
      out[g*256 + t]       = mx;
      out[g*256 + 128 + t] = sm / (float)K;
    } else {
      out[g*256 + t]       += mx;
      out[g*256 + 128 + t] += sm / (float)K;
    }
  }
  if (!HASNEXT) return;
  __syncthreads();

  if (t < K) sc[t] = 0;
  __syncthreads();
  for (int e = t; e < E_in; e += 1024){
    int rs = lnew[ss[e] & (NP-1)], rd = lnew[sd[e] & (NP-1)];
    bool ok = (rs | rd) >= 0;
    ss[e] = rs;
    sd[e] = ok ? rd : -1;
    if (ok) atomicAdd(&sc[rd], 1);
  }
  __syncthreads();
  int cv = 0; float dvn = 0.f;
  if (t < K){
    cv = sc[t];
    dvn = rsqrtf((float)cv + 1.f);
    sdvn[t] = dvn;
    dinv_o[g*K + t] = dvn;
    cnt_o[g*K + t] = cv;
    sp2[t] = cv;
  }
  __syncthreads();
  for (int d = 1; d < K; d <<= 1){
    int u = 0;
    if (t >= d && t < K) u = sp2[t-d];
    __syncthreads();
    if (t < K) sp2[t] += u;
    __syncthreads();
  }
  if (t < K){
    int pre = sp2[t] - cv;
    off_o[g*K + t] = g*EPG + pre;
    sc[t] = pre;
    cur[t] = 0;
    if (t == K-1) ecnt_o[g] = pre + cv;
  }
  __syncthreads();
  for (int e = t; e < E_in; e += 1024){
    int ndl = sd[e];
    if (ndl < 0) continue;
    int nsl = ss[e];
    int slot = sc[ndl] + atomicAdd(&cur[ndl], 1);
    csr_o[g*EPG + slot]  = g*K + nsl;
    dst_o[g*EPG + slot]  = g*K + ndl;
    coef_o[g*EPG + slot] = sdvn[nsl] * sdvn[ndl];
  }
}

// ---------------- host launcher ----------------
extern "C" void kernel_launch(void* const* d_in, const int* in_sizes, int n_in,
                              void* d_out, int out_size, void* d_ws, size_t ws_size,
                              hipStream_t stream){
  const float* x0 = (const float*)d_in[0];
  const int*   ei = (const int*)d_in[1];
  const float* Wl[3]  = {(const float*)d_in[3], (const float*)d_in[7],  (const float*)d_in[11]};
  const float* bl[3]  = {(const float*)d_in[4], (const float*)d_in[8],  (const float*)d_in[12]};
  const float* Wsl[3] = {(const float*)d_in[5], (const float*)d_in[9],  (const float*)d_in[13]};
  const float* bsl[3] = {(const float*)d_in[6], (const float*)d_in[10], (const float*)d_in[14]};

  // workspace layout (floats)
  float* A     = (float*)d_ws;                   // hx            65536*128
  float* C     = A + (size_t)65536*128;          // h (post agg)  65536*128
  float* D     = C + (size_t)65536*128;          // xnew / next x 32768*128
  float* dinvA = D + (size_t)32768*128;          // 65536
  float* dinvB = dinvA + 65536;                  // 65536
  float* hs    = dinvB + 65536;                  // 65536
  int* cntA    = (int*)(hs + 65536);             // 65536
  int* cntB    = cntA + 65536;                   // 65536
  int* offA    = cntB + 65536;                   // 65536
  int* offB    = offA + 65536;                   // 65536
  int* csrA    = offB + 65536;                   // 524288
  int* csrB    = csrA + ETOT;                    // 524288
  int* dstA    = csrB + ETOT;                    // 524288
  int* dstB    = dstA + ETOT;                    // 524288
  float* coefA = (float*)(dstB + ETOT);          // 524288
  float* coefB = coefA + ETOT;                   // 524288
  int* ecntA   = (int*)(coefB + ETOT);           // 128
  int* ecntB   = ecntA + 128;                    // 128

  float* out = (float*)d_out;

  // ---- level 1 (NP=512 -> K1=256): scanfill || dbuf gemm, 42 KB dynamic LDS ----
  size_t shbytes = (size_t)(2*(128*17) + 2*(16*192)) * sizeof(float);   // 41984 B
  fused_l1<<<640, 256, shbytes, stream>>>(x0, Wl[0], A,
      ei, ei + ETOT, offA, cntA, dinvA, csrA, coefA, ecntA);
  gather_agg<<<65536/8, 256, 0, stream>>>(A, csrA, coefA, offA, cntA, dinvA, bl[0], Wsl[0], C, hs, 512, 65536);
  mega<512, K1, 1, 1, 1><<<BGRAPH, 1024, 0, stream>>>(hs, csrA, coefA, offA, cntA, dinvA, bsl[0],
      C, D, out, ei, ei + ETOT, ecntA,
      offB, cntB, dinvB, csrB, dstB, coefB, ecntB);
  // ---- level 2 (NP=256 -> K2=128) ----
  gemm_db64<<<32768/64, 256, 0, stream>>>(D, Wl[1], A);
  gather_agg<<<32768/8, 256, 0, stream>>>(A, csrB, coefB, offB, cntB, dinvB, bl[1], Wsl[1], C, hs, 256, 32768);
  mega<256, K2, 1, 0, 0><<<BGRAPH, 1024, 0, stream>>>(hs, csrB, coefB, offB, cntB, dinvB, bsl[1],
      C, D, out, csrB, dstB, ecntB,
      offA, cntA, dinvA, csrA, dstA, coefA, ecntA);
  // ---- level 3 (NP=128 -> K3=64) ----
  gemm_db64<<<16384/64, 256, 0, stream>>>(D, Wl[2], A);
  gather_agg<<<16384/8, 256, 0, stream>>>(A, csrA, coefA, offA, cntA, dinvA, bl[2], Wsl[2], C, hs, 128, 16384);
  mega<128, K3, 0, 0, 0><<<BGRAPH, 1024, 0, stream>>>(hs, csrA, coefA, offA, cntA, dinvA, bsl[2],
      C, D, out, csrA, dstA, ecntA,
      offB, cntB, dinvB, csrB, dstB, coefB, ecntB);
}

// Round 17
// 170.885 us; speedup vs baseline: 1.1395x; 1.1395x over previous
//
#include <hip/hip_runtime.h>
#include <math.h>

#define BGRAPH 128
#define ETOT   (128*4096)   // 524288
#define EPG    4096
#define K1 256
#define K2 128
#define K3 64

// ---------------- tiled GEMM BM=64/BK=16 (conflict-free LDS, 16.6 KB) ----------------
__global__ __launch_bounds__(256) void gemm_64(const float* __restrict__ X,
                                               const float* __restrict__ W,
                                               float* __restrict__ Y){
  __shared__ float sA[64][17];
  __shared__ float sB[16][192];
  int t = threadIdx.x;
  int row0 = blockIdx.x * 64;
  int tx = t & 15;
  int ty = t >> 4;
  float acc[4][8];
  #pragma unroll
  for (int i = 0; i < 4; ++i)
    #pragma unroll
    for (int j = 0; j < 8; ++j) acc[i][j] = 0.f;

  for (int k0 = 0; k0 < 128; k0 += 16){
    {
      int row = t >> 2, c4 = t & 3;
      float4 v = *(const float4*)(X + (size_t)(row0 + row)*128 + k0 + c4*4);
      sA[row][c4*4+0] = v.x;
      sA[row][c4*4+1] = v.y;
      sA[row][c4*4+2] = v.z;
      sA[row][c4*4+3] = v.w;
    }
    #pragma unroll
    for (int i = 0; i < 2; ++i){
      int f = t + i*256;
      int kr = f >> 5, c4 = f & 31;
      float4 v = *(const float4*)(W + (size_t)(k0 + kr)*128 + c4*4);
      *(float4*)&sB[kr][(c4>>1)*12 + (c4&1)*4] = v;
    }
    __syncthreads();
    #pragma unroll
    for (int kk = 0; kk < 16; ++kk){
      float4 b0 = *(const float4*)&sB[kk][tx*12];
      float4 b1 = *(const float4*)&sB[kk][tx*12 + 4];
      float aa[4];
      #pragma unroll
      for (int i = 0; i < 4; ++i) aa[i] = sA[ty*4 + i][kk];
      float bb[8] = {b0.x,b0.y,b0.z,b0.w,b1.x,b1.y,b1.z,b1.w};
      #pragma unroll
      for (int i = 0; i < 4; ++i)
        #pragma unroll
        for (int j = 0; j < 8; ++j)
          acc[i][j] = fmaf(aa[i], bb[j], acc[i][j]);
    }
    __syncthreads();
  }
  #pragma unroll
  for (int i = 0; i < 4; ++i){
    float* yr = Y + (size_t)(row0 + ty*4 + i)*128 + tx*8;
    *(float4*)yr       = *(float4*)&acc[i][0];
    *(float4*)(yr + 4) = *(float4*)&acc[i][4];
  }
}

// ---------------- fused L1: blocks 0..1023 GEMM (BM=64), 1024..1151 scanfill ----------------
__global__ __launch_bounds__(256) void fused_l1(const float* __restrict__ X,
    const float* __restrict__ W, float* __restrict__ Y,
    const int* __restrict__ src, const int* __restrict__ dst,
    int* __restrict__ off, int* __restrict__ cnt, float* __restrict__ dinv,
    int* __restrict__ csr, float* __restrict__ coef, int* __restrict__ ecnt){
  extern __shared__ float smem[];
  int t = threadIdx.x;
  if (blockIdx.x < 1024){
    float* sA = smem;               // [64][17]
    float* sB = smem + 64*17;       // [16][192]
    int row0 = blockIdx.x * 64;
    int tx = t & 15;
    int ty = t >> 4;
    float acc[4][8];
    #pragma unroll
    for (int i = 0; i < 4; ++i)
      #pragma unroll
      for (int j = 0; j < 8; ++j) acc[i][j] = 0.f;

    for (int k0 = 0; k0 < 128; k0 += 16){
      {
        int row = t >> 2, c4 = t & 3;
        float4 v = *(const float4*)(X + (size_t)(row0 + row)*128 + k0 + c4*4);
        sA[row*17 + c4*4+0] = v.x;
        sA[row*17 + c4*4+1] = v.y;
        sA[row*17 + c4*4+2] = v.z;
        sA[row*17 + c4*4+3] = v.w;
      }
      #pragma unroll
      for (int i = 0; i < 2; ++i){
        int f = t + i*256;
        int kr = f >> 5, c4 = f & 31;
        float4 v = *(const float4*)(W + (size_t)(k0 + kr)*128 + c4*4);
        *(float4*)&sB[kr*192 + (c4>>1)*12 + (c4&1)*4] = v;
      }
      __syncthreads();
      #pragma unroll
      for (int kk = 0; kk < 16; ++kk){
        float4 b0 = *(const float4*)&sB[kk*192 + tx*12];
        float4 b1 = *(const float4*)&sB[kk*192 + tx*12 + 4];
        float aa[4];
        #pragma unroll
        for (int i = 0; i < 4; ++i) aa[i] = sA[(ty*4 + i)*17 + kk];
        float bb[8] = {b0.x,b0.y,b0.z,b0.w,b1.x,b1.y,b1.z,b1.w};
        #pragma unroll
        for (int i = 0; i < 4; ++i)
          #pragma unroll
          for (int j = 0; j < 8; ++j)
            acc[i][j] = fmaf(aa[i], bb[j], acc[i][j]);
      }
      __syncthreads();
    }
    #pragma unroll
    for (int i = 0; i < 4; ++i){
      float* yr = Y + (size_t)(row0 + ty*4 + i)*128 + tx*8;
      *(float4*)yr       = *(float4*)&acc[i][0];
      *(float4*)(yr + 4) = *(float4*)&acc[i][4];
    }
  } else {
    // scanfill: count -> scan -> fill
    int g = blockIdx.x - 1024;
    int*   sc  = (int*)smem;            // 512
    int*   sp  = sc + 512;              // 256
    int*   cur = sp + 256;              // 512
    float* sdv = (float*)(cur + 512);   // 512
    sc[t] = 0; sc[t + 256] = 0;
    __syncthreads();
    const int* sg = src + g*EPG;
    const int* dg = dst + g*EPG;
    for (int e = t; e < EPG; e += 256)
      atomicAdd(&sc[dg[e] & 511], 1);
    __syncthreads();
    int a = sc[2*t], b = sc[2*t+1];
    int pair = a + b;
    sp[t] = pair;
    __syncthreads();
    for (int d = 1; d < 256; d <<= 1){
      int u = (t >= d) ? sp[t-d] : 0;
      __syncthreads();
      sp[t] += u;
      __syncthreads();
    }
    int pre0 = sp[t] - pair;
    int pre1 = pre0 + a;
    float dv0 = rsqrtf((float)a + 1.f);
    float dv1 = rsqrtf((float)b + 1.f);
    sdv[2*t]   = dv0;  sdv[2*t+1] = dv1;
    dinv[g*512 + 2*t]   = dv0;  dinv[g*512 + 2*t+1] = dv1;
    cnt[g*512 + 2*t]    = a;    cnt[g*512 + 2*t+1]  = b;
    off[g*512 + 2*t]    = g*EPG + pre0;
    off[g*512 + 2*t+1]  = g*EPG + pre1;
    sc[2*t] = pre0; sc[2*t+1] = pre1;
    cur[2*t] = 0;   cur[2*t+1] = 0;
    if (t == 0) ecnt[g] = EPG;
    __syncthreads();
    int* cg = csr + g*EPG;
    float* cf = coef + g*EPG;
    for (int e = t; e < EPG; e += 256){
      int s = sg[e], dl = dg[e] & 511;
      int slot = sc[dl] + atomicAdd(&cur[dl], 1);
      cg[slot]  = s;
      cf[slot]  = sdv[s & 511] * sdv[dl];
    }
  }
}

// ---------------- fused aggregation + score GEMV, graph->XCD pinned, unroll x8 ----------------
__global__ void gather_agg(const float* __restrict__ hx, const int* __restrict__ csr,
                           const float* __restrict__ coef,
                           const int* __restrict__ off, const int* __restrict__ cnt,
                           const float* __restrict__ dinv, const float* __restrict__ bias,
                           const float* __restrict__ Ws, float* __restrict__ out,
                           float* __restrict__ hs, int npg, int n){
  int bpg = npg >> 3;
  int x = blockIdx.x >> 3, r = blockIdx.x & 7;
  int pos = x % bpg, grp = x / bpg;
  int g = grp*8 + r;
  int t = threadIdx.x;
  int node = g*npg + pos*8 + (t >> 5);
  int fl = t & 31;
  float dd = dinv[node];
  int o = off[node], deg = cnt[node];
  const float4* rows = (const float4*)hx;
  float4 a0 = {0,0,0,0}, a1 = {0,0,0,0}, a2 = {0,0,0,0}, a3 = {0,0,0,0};
  int e = o, end = o + deg;
  for (; e + 7 < end; e += 8){
    int sx[8]; float cx[8]; float4 vv[8];
    #pragma unroll
    for (int q = 0; q < 8; ++q){ sx[q] = csr[e+q]; cx[q] = coef[e+q]; }
    #pragma unroll
    for (int q = 0; q < 8; ++q) vv[q] = rows[(size_t)sx[q]*32 + fl];
    #pragma unroll
    for (int q = 0; q < 8; ++q){
      float4& aq = (q&3)==0 ? a0 : ((q&3)==1 ? a1 : ((q&3)==2 ? a2 : a3));
      aq.x = fmaf(cx[q], vv[q].x, aq.x);
      aq.y = fmaf(cx[q], vv[q].y, aq.y);
      aq.z = fmaf(cx[q], vv[q].z, aq.z);
      aq.w = fmaf(cx[q], vv[q].w, aq.w);
    }
  }
  for (; e + 3 < end; e += 4){
    int sx[4]; float cx[4]; float4 vv[4];
    #pragma unroll
    for (int q = 0; q < 4; ++q){ sx[q] = csr[e+q]; cx[q] = coef[e+q]; }
    #pragma unroll
    for (int q = 0; q < 4; ++q) vv[q] = rows[(size_t)sx[q]*32 + fl];
    #pragma unroll
    for (int q = 0; q < 4; ++q){
      float4& aq = (q==0) ? a0 : ((q==1) ? a1 : ((q==2) ? a2 : a3));
      aq.x = fmaf(cx[q], vv[q].x, aq.x);
      aq.y = fmaf(cx[q], vv[q].y, aq.y);
      aq.z = fmaf(cx[q], vv[q].z, aq.z);
      aq.w = fmaf(cx[q], vv[q].w, aq.w);
    }
  }
  for (; e < end; ++e){
    int s0 = csr[e];
    float c0 = coef[e];
    float4 v0 = rows[(size_t)s0*32 + fl];
    a0.x=fmaf(c0,v0.x,a0.x); a0.y=fmaf(c0,v0.y,a0.y); a0.z=fmaf(c0,v0.z,a0.z); a0.w=fmaf(c0,v0.w,a0.w);
  }
  float4 own = rows[(size_t)node*32 + fl];
  float4 bv  = ((const float4*)bias)[fl];
  float d2 = dd*dd;
  float4 rr;
  rr.x = fmaxf(fmaf(d2, own.x, (a0.x+a1.x)+(a2.x+a3.x) + bv.x), 0.f);
  rr.y = fmaxf(fmaf(d2, own.y, (a0.y+a1.y)+(a2.y+a3.y) + bv.y), 0.f);
  rr.z = fmaxf(fmaf(d2, own.z, (a0.z+a1.z)+(a2.z+a3.z) + bv.z), 0.f);
  rr.w = fmaxf(fmaf(d2, own.w, (a0.w+a1.w)+(a2.w+a3.w) + bv.w), 0.f);
  ((float4*)(out + (size_t)node*128))[fl] = rr;
  float4 w = ((const float4*)Ws)[fl];
  float p = rr.x*w.x + rr.y*w.y + rr.z*w.z + rr.w*w.w;
  p += __shfl_xor(p, 16);
  p += __shfl_xor(p, 8);
  p += __shfl_xor(p, 4);
  p += __shfl_xor(p, 2);
  p += __shfl_xor(p, 1);
  if (fl == 0) hs[node] = p;
}

// ---------------- per-graph mega (1024 thr) ----------------
template<int NP, int K, int HASNEXT, int FIRST, int RAW>
__global__ __launch_bounds__(1024) void mega(
    const float* __restrict__ hs, const int* __restrict__ csr_in,
    const float* __restrict__ coef_in, const int* __restrict__ off_in,
    const int* __restrict__ cnt_in, const float* __restrict__ dinv_in,
    const float* __restrict__ bs, const float* __restrict__ Hm,
    float* __restrict__ xnew, float* __restrict__ out,
    const int* __restrict__ pes, const int* __restrict__ ped,
    const int* __restrict__ ecnt_in,
    int* __restrict__ off_o, int* __restrict__ cnt_o, float* __restrict__ dinv_o,
    int* __restrict__ csr_o, int* __restrict__ dst_o, float* __restrict__ coef_o,
    int* __restrict__ ecnt_o)
{
  constexpr int R   = 1024 / NP;
  constexpr int LNP = (NP == 512) ? 9 : ((NP == 256) ? 8 : 7);
  __shared__ int   ss[EPG];
  __shared__ int   sd[EPG];
  __shared__ float scf[RAW ? 1 : EPG];
  __shared__ float shs[NP];
  __shared__ float spart[1024];
  __shared__ float sv[NP];
  __shared__ int   si[NP];
  __shared__ int   lnew[NP];
  __shared__ int   lperm[K];
  __shared__ float ltanh[K];
  __shared__ float smx[1024], ssm[1024];
  __shared__ int   sc[K], sp2[K], cur[K];
  __shared__ float sdvn[K];
  int g = blockIdx.x, t = threadIdx.x;
  int E_in = ecnt_in[g];

  if (t < NP){ shs[t] = hs[g*NP + t]; lnew[t] = -1; }
  for (int e = t; e < E_in; e += 1024){
    ss[e] = pes[g*EPG + e];
    sd[e] = ped[g*EPG + e];
    if (!RAW) scf[e] = coef_in[g*EPG + e];
  }
  __syncthreads();

  int n = t & (NP-1);
  int p = t >> LNP;
  {
    float a = 0.f;
    if (RAW){
      int lo = off_in[g*NP + n], deg = cnt_in[g*NP + n];
      for (int e = lo + p; e < lo + deg; e += R)
        a = fmaf(coef_in[e], shs[csr_in[e] & (NP-1)], a);
    } else {
      int lo = off_in[g*NP + n] - g*EPG, deg = cnt_in[g*NP + n];
      for (int e = lo + p; e < lo + deg; e += R)
        a = fmaf(scf[e], shs[ss[e] & (NP-1)], a);
    }
    spart[t] = a;
  }
  __syncthreads();
  float v = -INFINITY; int idx = n;
  if (p == 0){
    float a = spart[n];
    #pragma unroll
    for (int q = 1; q < R; ++q) a += spart[n + q*NP];
    float dd = dinv_in[g*NP + n];
    v = a + fmaf(dd*dd, shs[n], bs[0]);
  }
  #pragma unroll
  for (int ksz = 2; ksz <= NP; ksz <<= 1){
    #pragma unroll
    for (int j = ksz >> 1; j > 0; j >>= 1){
      float v2 = 0.f; int i2 = 0;
      if (j >= 64){
        __syncthreads();
        if (t < NP){ sv[t] = v; si[t] = idx; }
        __syncthreads();
        if (t < NP){ v2 = sv[t^j]; i2 = si[t^j]; }
      } else if (t < NP){
        v2 = __shfl_xor(v, j);
        i2 = __shfl_xor(idx, j);
      }
      if (t < NP){
        bool dir = ((t & ksz) == 0);
        bool pf = (v2 > v) || (v2 == v && i2 < idx);
        bool lower = (t & j) == 0;
        if (pf == (lower ? dir : !dir)){ v = v2; idx = i2; }
      }
    }
  }
  if (t < K){
    lperm[t] = idx;
    lnew[idx] = t;
    ltanh[t] = tanhf(v);
  }
  __syncthreads();

  {
    int f = t & 127, q = t >> 7;
    float mx = -INFINITY, sm = 0.f;
    for (int j = q; j < K; j += 8){
      float val = Hm[(size_t)(g*NP + lperm[j])*128 + f] * ltanh[j];
      xnew[(size_t)(g*K + j)*128 + f] = val;
      mx = fmaxf(mx, val); sm += val;
    }
    smx[t] = mx; ssm[t] = sm;
  }
  __syncthreads();
  if (t < 128){
    float mx = smx[t], sm = ssm[t];
    #pragma unroll
    for (int q = 1; q < 8; ++q){ mx = fmaxf(mx, smx[q*128+t]); sm += ssm[q*128+t]; }
    if (FIRST){
      out[g*256 + t]       = mx;
      out[g*256 + 128 + t] = sm / (float)K;
    } else {
      out[g*256 + t]       += mx;
      out[g*256 + 128 + t] += sm / (float)K;
    }
  }
  if (!HASNEXT) return;
  __syncthreads();

  if (t < K) sc[t] = 0;
  __syncthreads();
  for (int e = t; e < E_in; e += 1024){
    int rs = lnew[ss[e] & (NP-1)], rd = lnew[sd[e] & (NP-1)];
    bool ok = (rs | rd) >= 0;
    ss[e] = rs;
    sd[e] = ok ? rd : -1;
    if (ok) atomicAdd(&sc[rd], 1);
  }
  __syncthreads();
  int cv = 0; float dvn = 0.f;
  if (t < K){
    cv = sc[t];
    dvn = rsqrtf((float)cv + 1.f);
    sdvn[t] = dvn;
    dinv_o[g*K + t] = dvn;
    cnt_o[g*K + t] = cv;
    sp2[t] = cv;
  }
  __syncthreads();
  for (int d = 1; d < K; d <<= 1){
    int u = 0;
    if (t >= d && t < K) u = sp2[t-d];
    __syncthreads();
    if (t < K) sp2[t] += u;
    __syncthreads();
  }
  if (t < K){
    int pre = sp2[t] - cv;
    off_o[g*K + t] = g*EPG + pre;
    sc[t] = pre;
    cur[t] = 0;
    if (t == K-1) ecnt_o[g] = pre + cv;
  }
  __syncthreads();
  for (int e = t; e < E_in; e += 1024){
    int ndl = sd[e];
    if (ndl < 0) continue;
    int nsl = ss[e];
    int slot = sc[ndl] + atomicAdd(&cur[ndl], 1);
    csr_o[g*EPG + slot]  = g*K + nsl;
    dst_o[g*EPG + slot]  = g*K + ndl;
    coef_o[g*EPG + slot] = sdvn[nsl] * sdvn[ndl];
  }
}

// ---------------- host launcher ----------------
extern "C" void kernel_launch(void* const* d_in, const int* in_sizes, int n_in,
                              void* d_out, int out_size, void* d_ws, size_t ws_size,
                              hipStream_t stream){
  const float* x0 = (const float*)d_in[0];
  const int*   ei = (const int*)d_in[1];
  const float* Wl[3]  = {(const float*)d_in[3], (const float*)d_in[7],  (const float*)d_in[11]};
  const float* bl[3]  = {(const float*)d_in[4], (const float*)d_in[8],  (const float*)d_in[12]};
  const float* Wsl[3] = {(const float*)d_in[5], (const float*)d_in[9],  (const float*)d_in[13]};
  const float* bsl[3] = {(const float*)d_in[6], (const float*)d_in[10], (const float*)d_in[14]};

  // workspace layout (floats)
  float* A     = (float*)d_ws;                   // hx            65536*128
  float* C     = A + (size_t)65536*128;          // h (post agg)  65536*128
  float* D     = C + (size_t)65536*128;          // xnew / next x 32768*128
  float* dinvA = D + (size_t)32768*128;          // 65536
  float* dinvB = dinvA + 65536;                  // 65536
  float* hs    = dinvB + 65536;                  // 65536
  int* cntA    = (int*)(hs + 65536);             // 65536
  int* cntB    = cntA + 65536;                   // 65536
  int* offA    = cntB + 65536;                   // 65536
  int* offB    = offA + 65536;                   // 65536
  int* csrA    = offB + 65536;                   // 524288
  int* csrB    = csrA + ETOT;                    // 524288
  int* dstA    = csrB + ETOT;                    // 524288
  int* dstB    = dstA + ETOT;                    // 524288
  float* coefA = (float*)(dstB + ETOT);          // 524288
  float* coefB = coefA + ETOT;                   // 524288
  int* ecntA   = (int*)(coefB + ETOT);           // 128
  int* ecntB   = ecntA + 128;                    // 128

  float* out = (float*)d_out;

  // ---- level 1 (NP=512 -> K1=256): scanfill || gemm (BM=64), 16.6 KB dynamic LDS ----
  size_t shbytes = (size_t)(64*17 + 16*192) * sizeof(float);   // 16640 B
  fused_l1<<<1152, 256, shbytes, stream>>>(x0, Wl[0], A,
      ei, ei + ETOT, offA, cntA, dinvA, csrA, coefA, ecntA);
  gather_agg<<<65536/8, 256, 0, stream>>>(A, csrA, coefA, offA, cntA, dinvA, bl[0], Wsl[0], C, hs, 512, 65536);
  mega<512, K1, 1, 1, 1><<<BGRAPH, 1024, 0, stream>>>(hs, csrA, coefA, offA, cntA, dinvA, bsl[0],
      C, D, out, ei, ei + ETOT, ecntA,
      offB, cntB, dinvB, csrB, dstB, coefB, ecntB);
  // ---- level 2 (NP=256 -> K2=128) ----
  gemm_64<<<32768/64, 256, 0, stream>>>(D, Wl[1], A);
  gather_agg<<<32768/8, 256, 0, stream>>>(A, csrB, coefB, offB, cntB, dinvB, bl[1], Wsl[1], C, hs, 256, 32768);
  mega<256, K2, 1, 0, 0><<<BGRAPH, 1024, 0, stream>>>(hs, csrB, coefB, offB, cntB, dinvB, bsl[1],
      C, D, out, csrB, dstB, ecntB,
      offA, cntA, dinvA, csrA, dstA, coefA, ecntA);
  // ---- level 3 (NP=128 -> K3=64) ----
  gemm_64<<<16384/64, 256, 0, stream>>>(D, Wl[2], A);
  gather_agg<<<16384/8, 256, 0, stream>>>(A, csrA, coefA, offA, cntA, dinvA, bl[2], Wsl[2], C, hs, 128, 16384);
  mega<128, K3, 0, 0, 0><<<BGRAPH, 1024, 0, stream>>>(hs, csrA, coefA, offA, cntA, dinvA, bsl[2],
      C, D, out, csrA, dstA, ecntA,
      offB, cntB, dinvB, csrB, dstB, coefB, ecntB);
}